// Round 13
// baseline (846.464 us; speedup 1.0000x reference)
//
#include <hip/hip_runtime.h>

#define H 128
#define D 2
#define T_OBS 20
#define BATCH 16384
#define PRED 30
#define M 32          // batch rows per block (two 16-row MFMA tiles)
#define NTH 512       // 8 waves; wave wv owns units 16*wv .. 16*wv+15 (all 4 gates)
#define HP 136        // padded fp16 h-row stride
#define FP 132        // padded f32 row stride
#define LN_EPS 1e-5f

typedef __attribute__((ext_vector_type(8))) _Float16 half8_t;
typedef __attribute__((ext_vector_type(4))) float float4_t;

__device__ __forceinline__ float fast_rcp(float x){ return __builtin_amdgcn_rcpf(x); }
__device__ __forceinline__ float sig_f(float x){ return fast_rcp(1.f + __expf(-x)); }
// PINNED: explicit fmaf (R9's unpinned 1-2*rcp was the last contraction lottery site)
__device__ __forceinline__ float tanh_f(float x){ return fmaf(-2.f, fast_rcp(__expf(2.f*x)+1.f), 1.f); }

// Per-phase per-wave constants: bw 64 VGPR + consts 12; acc 32 AGPR.
// Total ~123 incl AGPR -> fits the 128-reg budget of __launch_bounds__(512,4)
// -> 2 blocks/CU (LDS 79872*2 = 159744 <= 163840).
struct PhaseConsts {
  half8_t bw[4][4];
  float bs[4], w0[4], w1[4];
};

__device__ __forceinline__ void load_phase(PhaseConsts& P, const float* __restrict__ Whh,
                                           const float* __restrict__ Wih,
                                           const float* __restrict__ bih,
                                           const float* __restrict__ bhh,
                                           int wv, int l15, int q){
#pragma unroll
  for(int g=0; g<4; g++){
    const int n = g*H + 16*wv + l15;
    P.bs[g] = bih[n] + bhh[n];
    P.w0[g] = Wih[n*D + 0];
    P.w1[g] = Wih[n*D + 1];
#pragma unroll
    for(int ks=0; ks<4; ks++){
      const float* p = Whh + (size_t)n*H + ks*32 + q*8;  // B[k][n]=Whh[n][k]
      float4 a = *(const float4*)p;
      float4 b = *(const float4*)(p+4);
      half8_t f;
      f[0]=(_Float16)a.x; f[1]=(_Float16)a.y; f[2]=(_Float16)a.z; f[3]=(_Float16)a.w;
      f[4]=(_Float16)b.x; f[5]=(_Float16)b.y; f[6]=(_Float16)b.z; f[7]=(_Float16)b.w;
      P.bw[g][ks] = f;
    }
  }
}

// Decoder fold: Wcomb = Whh + Wih*Wfc, b' = b + Wih*bfc.
// PINNED: explicit fmaf, single rounding, build-invariant
// (1-bf16-ulp output in every fully-pinned build: R11, R12).
__device__ __forceinline__ void load_phase_dec(PhaseConsts& P, const float* __restrict__ Whh,
                                               const float* __restrict__ Wih,
                                               const float* __restrict__ bih,
                                               const float* __restrict__ bhh,
                                               const float* __restrict__ Wfc,
                                               const float* __restrict__ bfc,
                                               int wv, int l15, int q){
#pragma unroll
  for(int g=0; g<4; g++){
    const int n = g*H + 16*wv + l15;
    const float wi0 = Wih[n*D + 0];
    const float wi1 = Wih[n*D + 1];
    P.bs[g] = fmaf(wi1, bfc[1], fmaf(wi0, bfc[0], bih[n] + bhh[n]));
    P.w0[g] = wi0;
    P.w1[g] = wi1;
#pragma unroll
    for(int ks=0; ks<4; ks++){
      const float* p  = Whh + (size_t)n*H + ks*32 + q*8;
      const float* f0 = Wfc + 0*H + ks*32 + q*8;
      const float* f1 = Wfc + 1*H + ks*32 + q*8;
      half8_t f;
#pragma unroll
      for(int j=0;j<8;j++){
        f[j] = (_Float16)fmaf(wi1, f1[j], fmaf(wi0, f0[j], p[j]));
      }
      P.bw[g][ks] = f;
    }
  }
}

// One LSTM cell step for 32 rows (two 16-row m-halves, independent accumulators).
// h read from hsh[cur] (single fp16 plane), x from xsrc[32][2] (only when HASX),
// new h written to hsh[cur^1]. c per-lane fp32. One barrier.
template<bool HASX>
__device__ __forceinline__ void cell_step(_Float16 (*hsh)[M][HP], int cur,
                                          const float* __restrict__ xsrc,
                                          const PhaseConsts& P, float (&c)[2][4],
                                          int wv, int l15, int q){
  float4_t acc[2][4];
  if constexpr (HASX){
#pragma unroll
    for(int mh=0; mh<2; mh++){
      float x0[4], x1[4];
#pragma unroll
      for(int r=0; r<4; r++){
        x0[r] = xsrc[(mh*16 + 4*q+r)*2 + 0];
        x1[r] = xsrc[(mh*16 + 4*q+r)*2 + 1];
      }
#pragma unroll
      for(int g=0; g<4; g++)
#pragma unroll
        for(int r=0; r<4; r++)
          acc[mh][g][r] = fmaf(P.w1[g], x1[r], fmaf(P.w0[g], x0[r], P.bs[g]));
    }
  } else {
#pragma unroll
    for(int mh=0; mh<2; mh++)
#pragma unroll
      for(int g=0; g<4; g++)
#pragma unroll
        for(int r=0; r<4; r++)
          acc[mh][g][r] = P.bs[g];
  }

#pragma unroll
  for(int ks=0; ks<4; ks++){
#pragma unroll
    for(int mh=0; mh<2; mh++){
      const half8_t a = *(const half8_t*)&hsh[cur][mh*16 + l15][ks*32 + q*8];
#pragma unroll
      for(int g=0; g<4; g++){
        acc[mh][g] = __builtin_amdgcn_mfma_f32_16x16x32_f16(a, P.bw[g][ks], acc[mh][g], 0,0,0);
      }
    }
  }
  const int nxt = cur ^ 1;
  const int u = 16*wv + l15;
#pragma unroll
  for(int mh=0; mh<2; mh++){
#pragma unroll
    for(int r=0; r<4; r++){
      const float iv = sig_f(acc[mh][0][r]);
      const float fv = sig_f(acc[mh][1][r]);
      const float gv = tanh_f(acc[mh][2][r]);
      const float ov = sig_f(acc[mh][3][r]);
      const float cc = fmaf(fv, c[mh][r], iv*gv);
      c[mh][r] = cc;
      const float hv = ov * tanh_f(cc);
      const int m = mh*16 + 4*q + r;
      hsh[nxt][m][u] = (_Float16)hv;
    }
  }
  __syncthreads();
}

// LayerNorm over 128 units for 32 rows; all 512 threads, 16 threads/row.
__device__ __forceinline__ void layernorm32(const float (*src)[FP], float (*dst)[FP],
                                            const float* __restrict__ g,
                                            const float* __restrict__ b, int tid){
  const int m = tid >> 4, sub = tid & 15;
  float v[8];
  float s = 0.f, s2 = 0.f;
#pragma unroll
  for(int j=0;j<8;j++){ v[j] = src[m][sub*8+j]; s += v[j]; s2 = fmaf(v[j], v[j], s2); }
#pragma unroll
  for(int msk=1; msk<16; msk<<=1){ s += __shfl_xor(s, msk, 64); s2 += __shfl_xor(s2, msk, 64); }
  const float mean = s * (1.f/H);
  const float var  = fmaf(-mean, mean, s2 * (1.f/H));   // PINNED contraction
  const float inv  = rsqrtf(var + LN_EPS);
#pragma unroll
  for(int j=0;j<8;j++){
    const int u = sub*8+j;
    dst[m][u] = fmaf((v[j]-mean)*inv, g[u], b[u]);
  }
}

// Output-only FC: cs = h @ Wfc^T + bfc from the fp16 plane; writes global out ONLY.
// No barrier needed: hb rewritten two cell-steps later (barrier in between).
__device__ __forceinline__ void fc_out(const _Float16 (*hb)[HP], const float (*wfc)[H],
                                       const float* __restrict__ bfcs,
                                       float* __restrict__ gout, int row0, int tid){
  const int m = tid >> 4, d = (tid >> 3) & 1, ch = tid & 7;
  const _Float16* hp = &hb[m][ch*16];
  float s = 0.f;
#pragma unroll
  for(int j=0;j<16;j++) s = fmaf((float)hp[j], wfc[d][ch*16+j], s);
  s += __shfl_xor(s, 1, 64); s += __shfl_xor(s, 2, 64); s += __shfl_xor(s, 4, 64);
  if(ch == 0){
    gout[(size_t)(row0+m)*D + d] = s + bfcs[d];
  }
}

// Step-0 delta: xb[m][d] = xlast[m][d] - (Wfc@h0 + bfc)[m][d]. All 512 threads.
__device__ __forceinline__ void fc_delta(const _Float16 (*hb)[HP], const float (*wfc)[H],
                                         const float* __restrict__ bfcs,
                                         const float* __restrict__ xlast,  // [M][D] contiguous
                                         float (*xb)[D], int tid){
  const int m = tid >> 4, d = (tid >> 3) & 1, ch = tid & 7;
  const _Float16* hp = &hb[m][ch*16];
  float s = 0.f;
#pragma unroll
  for(int j=0;j<16;j++) s = fmaf((float)hp[j], wfc[d][ch*16+j], s);
  s += __shfl_xor(s, 1, 64); s += __shfl_xor(s, 2, 64); s += __shfl_xor(s, 4, 64);
  if(ch == 0){
    xb[m][d] = xlast[m*D + d] - (s + bfcs[d]);
  }
}

__global__ __launch_bounds__(NTH, 4) void traj_kernel(
    const float* __restrict__ pos, const float* __restrict__ speed,
    const float* __restrict__ Wih_pe, const float* __restrict__ Whh_pe,
    const float* __restrict__ bih_pe, const float* __restrict__ bhh_pe,
    const float* __restrict__ Wih_se, const float* __restrict__ Whh_se,
    const float* __restrict__ bih_se, const float* __restrict__ bhh_se,
    const float* __restrict__ ln_g, const float* __restrict__ ln_b,
    const float* __restrict__ Wih_sd, const float* __restrict__ Whh_sd,
    const float* __restrict__ bih_sd, const float* __restrict__ bhh_sd,
    const float* __restrict__ Wih_pd, const float* __restrict__ Whh_pd,
    const float* __restrict__ bih_pd, const float* __restrict__ bhh_pd,
    const float* __restrict__ Wfc, const float* __restrict__ bfc,
    float* __restrict__ out)
{
  __shared__ __align__(16) _Float16 hsh[2][M][HP];    // [buf][m][u]  ~17.4 KB
  __shared__ float tmpf[M][FP];                        // ~16.9 KB each
  __shared__ float hpoN[M][FP];
  __shared__ float cpoN[M][FP];
  __shared__ float seqx[2][T_OBS][M][D];               // ~10.2 KB
  __shared__ float xbuf[M][D];
  __shared__ float wfcs[D][H];
  __shared__ float bfcs[2];
  // total ~79.6 KB -> 2 blocks/CU at the 128-reg budget

  const int tid  = threadIdx.x;
  const int lane = tid & 63;
  const int wv   = tid >> 6;       // 0..7 -> unit group
  const int q    = lane >> 4;
  const int l15  = lane & 15;
  const int row0 = blockIdx.x * M;
  const int u    = 16*wv + l15;

  // ---- stage inputs ----
  for(int idx = tid; idx < 2*T_OBS*M*D; idx += NTH){
    const int chain = idx / (T_OBS*M*D);
    const int rem   = idx % (T_OBS*M*D);
    const int t = rem / (M*D), e = rem % (M*D);
    const float* src = chain ? speed : pos;
    seqx[chain][t][e>>1][e&1] = src[(size_t)t*BATCH*D + row0*D + e];
  }
  if(tid < D*H) wfcs[tid>>7][tid&127] = Wfc[tid];
  if(tid < 2)   bfcs[tid] = bfc[tid];
  { int* hz = (int*)&hsh[0][0][0];                    // zero buf0 (M*HP fp16 = 2176 ints)
    for(int idx = tid; idx < M*HP/2; idx += NTH) hz[idx] = 0; }

  PhaseConsts P;
  float c[2][4];
  load_phase(P, Whh_pe, Wih_pe, bih_pe, bhh_pe, wv, l15, q);
#pragma unroll
  for(int mh=0;mh<2;mh++)
#pragma unroll
    for(int r=0;r<4;r++) c[mh][r] = 0.f;
  __syncthreads();

  // ---------- phase 1: pos encoder ----------
  int cur = 0;
  for(int t=0; t<T_OBS; t++){ cell_step<true>(hsh, cur, &seqx[0][t][0][0], P, c, wv, l15, q); cur ^= 1; }
  for(int idx=tid; idx<M*H; idx+=NTH){
    const int m = idx>>7, uu = idx&127;
    tmpf[m][uu] = (float)hsh[cur][m][uu];
  }
  __syncthreads();
  layernorm32(tmpf, hpoN, ln_g, ln_b, tid);
  __syncthreads();
#pragma unroll
  for(int mh=0;mh<2;mh++)
#pragma unroll
    for(int r=0;r<4;r++) tmpf[mh*16 + 4*q+r][u] = c[mh][r];
  __syncthreads();
  layernorm32(tmpf, cpoN, ln_g, ln_b, tid);
  __syncthreads();

  // ---------- phase 2: speed encoder ----------
  load_phase(P, Whh_se, Wih_se, bih_se, bhh_se, wv, l15, q);
#pragma unroll
  for(int mh=0;mh<2;mh++)
#pragma unroll
    for(int r=0;r<4;r++) c[mh][r] = 0.f;
  for(int idx=tid; idx<M*H; idx+=NTH){
    const int m = idx>>7, uu = idx&127;
    hsh[0][m][uu] = (_Float16)0.f;
  }
  cur = 0;
  __syncthreads();
  for(int t=0; t<T_OBS; t++){ cell_step<true>(hsh, cur, &seqx[1][t][0][0], P, c, wv, l15, q); cur ^= 1; }
  for(int idx=tid; idx<M*H; idx+=NTH){
    const int m = idx>>7, uu = idx&127;
    tmpf[m][uu] = (float)hsh[cur][m][uu];
  }
  __syncthreads();
  layernorm32(tmpf, tmpf, ln_g, ln_b, tid);
  __syncthreads();
  // hds = LN(hsp) + LN(hpo) -> hsh[0]
  for(int idx=tid; idx<M*H; idx+=NTH){
    const int m = idx>>7, uu = idx&127;
    hsh[0][m][uu] = (_Float16)(tmpf[m][uu] + hpoN[m][uu]);
  }
  __syncthreads();
  // cds = LN(csp) + LN(cpo)
#pragma unroll
  for(int mh=0;mh<2;mh++)
#pragma unroll
    for(int r=0;r<4;r++) tmpf[mh*16 + 4*q+r][u] = c[mh][r];
  __syncthreads();
  layernorm32(tmpf, tmpf, ln_g, ln_b, tid);
  __syncthreads();
#pragma unroll
  for(int mh=0;mh<2;mh++)
#pragma unroll
    for(int r=0;r<4;r++) c[mh][r] = tmpf[mh*16 + 4*q+r][u] + cpoN[mh*16 + 4*q+r][u];

  // ---------- phase 3: speed decoder (FC folded into recurrence) ----------
  load_phase_dec(P, Whh_sd, Wih_sd, bih_sd, bhh_sd, Wfc, bfc, wv, l15, q);
  // dx = x0 - (Wfc@h0 + bfc); h0 = hds already in hsh[0] (visible: barrier above)
  fc_delta(hsh[0], wfcs, bfcs, &seqx[1][T_OBS-1][0][0], xbuf, tid);
  __syncthreads();

  float* spd_out = out + (size_t)PRED*BATCH*D;
  cur = 0;
  cell_step<true>(hsh, cur, &xbuf[0][0], P, c, wv, l15, q);
  fc_out(hsh[cur^1], wfcs, bfcs, spd_out, row0, tid);
  cur ^= 1;
  for(int t=1; t<PRED; t++){
    cell_step<false>(hsh, cur, nullptr, P, c, wv, l15, q);
    fc_out(hsh[cur^1], wfcs, bfcs, spd_out + (size_t)t*BATCH*D, row0, tid);
    cur ^= 1;
  }
  __syncthreads();   // protect hsh buffer still being read by last fc_out before reuse

  // ---------- phase 4: pos decoder ----------
  for(int idx=tid; idx<M*H; idx+=NTH){
    const int m = idx>>7, uu = idx&127;
    hsh[0][m][uu] = (_Float16)hpoN[m][uu];
  }
#pragma unroll
  for(int mh=0;mh<2;mh++)
#pragma unroll
    for(int r=0;r<4;r++) c[mh][r] = cpoN[mh*16 + 4*q+r][u];
  load_phase_dec(P, Whh_pd, Wih_pd, bih_pd, bhh_pd, Wfc, bfc, wv, l15, q);
  __syncthreads();   // hsh[0] (h0 = LN(hpo)) visible
  fc_delta(hsh[0], wfcs, bfcs, &seqx[0][T_OBS-1][0][0], xbuf, tid);
  __syncthreads();   // xbuf visible

  cur = 0;
  cell_step<true>(hsh, cur, &xbuf[0][0], P, c, wv, l15, q);
  fc_out(hsh[cur^1], wfcs, bfcs, out, row0, tid);
  cur ^= 1;
  for(int t=1; t<PRED; t++){
    cell_step<false>(hsh, cur, nullptr, P, c, wv, l15, q);
    fc_out(hsh[cur^1], wfcs, bfcs, out + (size_t)t*BATCH*D, row0, tid);
    cur ^= 1;
  }
}

extern "C" void kernel_launch(void* const* d_in, const int* in_sizes, int n_in,
                              void* d_out, int out_size, void* d_ws, size_t ws_size,
                              hipStream_t stream)
{
  const float* pos    = (const float*)d_in[0];
  const float* speed  = (const float*)d_in[1];
  const float* Wih_pe = (const float*)d_in[2];
  const float* Whh_pe = (const float*)d_in[3];
  const float* bih_pe = (const float*)d_in[4];
  const float* bhh_pe = (const float*)d_in[5];
  const float* Wih_se = (const float*)d_in[6];
  const float* Whh_se = (const float*)d_in[7];
  const float* bih_se = (const float*)d_in[8];
  const float* bhh_se = (const float*)d_in[9];
  const float* ln_g   = (const float*)d_in[10];
  const float* ln_b   = (const float*)d_in[11];
  const float* Wih_sd = (const float*)d_in[12];
  const float* Whh_sd = (const float*)d_in[13];
  const float* bih_sd = (const float*)d_in[14];
  const float* bhh_sd = (const float*)d_in[15];
  const float* Wih_pd = (const float*)d_in[16];
  const float* Whh_pd = (const float*)d_in[17];
  const float* bih_pd = (const float*)d_in[18];
  const float* bhh_pd = (const float*)d_in[19];
  const float* Wfc    = (const float*)d_in[20];
  const float* bfc    = (const float*)d_in[21];

  traj_kernel<<<BATCH/M, NTH, 0, stream>>>(
      pos, speed, Wih_pe, Whh_pe, bih_pe, bhh_pe,
      Wih_se, Whh_se, bih_se, bhh_se, ln_g, ln_b,
      Wih_sd, Whh_sd, bih_sd, bhh_sd, Wih_pd, Whh_pd, bih_pd, bhh_pd,
      Wfc, bfc, (float*)d_out);
}

// Round 14
// 546.460 us; speedup vs baseline: 1.5490x; 1.5490x over previous
//
#include <hip/hip_runtime.h>

#define H 128
#define D 2
#define T_OBS 20
#define BATCH 16384
#define PRED 30
#define M 32          // batch rows per block (two 16-row MFMA tiles)
#define NTH 512       // 8 waves; wave wv owns units 16*wv .. 16*wv+15 (all 4 gates)
#define HP 136        // padded fp16 h-row stride
#define FP 132        // padded f32 row stride
#define LN_EPS 1e-5f

typedef __attribute__((ext_vector_type(8))) _Float16 half8_t;
typedef __attribute__((ext_vector_type(4))) float float4_t;

__device__ __forceinline__ float fast_rcp(float x){ return __builtin_amdgcn_rcpf(x); }
__device__ __forceinline__ float sig_f(float x){ return fast_rcp(1.f + __expf(-x)); }
// PINNED: explicit fmaf — fully-pinned builds are 3-for-3 at exactly 1 bf16 ulp (R11/R12/R13)
__device__ __forceinline__ float tanh_f(float x){ return fmaf(-2.f, fast_rcp(__expf(2.f*x)+1.f), 1.f); }

// LDS-only barrier: __syncthreads() emits s_waitcnt vmcnt(0) lgkmcnt(0); the
// vmcnt(0) forces each decoder step to drain fc_out's global stores (write-only,
// unique addresses, never re-read -> draining is pure stall). All inter-wave
// communication in the step loop is through LDS; lgkmcnt(0) covers it.
__device__ __forceinline__ void lds_barrier(){
  asm volatile("s_waitcnt lgkmcnt(0)\n\ts_barrier" ::: "memory");
}

// Per-phase per-wave constants: bw 64 VGPR + consts 12; acc 32 AGPR.
// (512,2) is the ONLY non-spilling envelope (R7/R8/R11/R12/R13: every other
// bound makes the allocator split 64/64 arch/accum and spill bw — GBs of scratch).
struct PhaseConsts {
  half8_t bw[4][4];
  float bs[4], w0[4], w1[4];
};

__device__ __forceinline__ void load_phase(PhaseConsts& P, const float* __restrict__ Whh,
                                           const float* __restrict__ Wih,
                                           const float* __restrict__ bih,
                                           const float* __restrict__ bhh,
                                           int wv, int l15, int q){
#pragma unroll
  for(int g=0; g<4; g++){
    const int n = g*H + 16*wv + l15;
    P.bs[g] = bih[n] + bhh[n];
    P.w0[g] = Wih[n*D + 0];
    P.w1[g] = Wih[n*D + 1];
#pragma unroll
    for(int ks=0; ks<4; ks++){
      const float* p = Whh + (size_t)n*H + ks*32 + q*8;  // B[k][n]=Whh[n][k]
      float4 a = *(const float4*)p;
      float4 b = *(const float4*)(p+4);
      half8_t f;
      f[0]=(_Float16)a.x; f[1]=(_Float16)a.y; f[2]=(_Float16)a.z; f[3]=(_Float16)a.w;
      f[4]=(_Float16)b.x; f[5]=(_Float16)b.y; f[6]=(_Float16)b.z; f[7]=(_Float16)b.w;
      P.bw[g][ks] = f;
    }
  }
}

// Decoder fold: Wcomb = Whh + Wih*Wfc, b' = b + Wih*bfc.
// PINNED: explicit fmaf, single rounding, build-invariant.
__device__ __forceinline__ void load_phase_dec(PhaseConsts& P, const float* __restrict__ Whh,
                                               const float* __restrict__ Wih,
                                               const float* __restrict__ bih,
                                               const float* __restrict__ bhh,
                                               const float* __restrict__ Wfc,
                                               const float* __restrict__ bfc,
                                               int wv, int l15, int q){
#pragma unroll
  for(int g=0; g<4; g++){
    const int n = g*H + 16*wv + l15;
    const float wi0 = Wih[n*D + 0];
    const float wi1 = Wih[n*D + 1];
    P.bs[g] = fmaf(wi1, bfc[1], fmaf(wi0, bfc[0], bih[n] + bhh[n]));
    P.w0[g] = wi0;
    P.w1[g] = wi1;
#pragma unroll
    for(int ks=0; ks<4; ks++){
      const float* p  = Whh + (size_t)n*H + ks*32 + q*8;
      const float* f0 = Wfc + 0*H + ks*32 + q*8;
      const float* f1 = Wfc + 1*H + ks*32 + q*8;
      half8_t f;
#pragma unroll
      for(int j=0;j<8;j++){
        f[j] = (_Float16)fmaf(wi1, f1[j], fmaf(wi0, f0[j], p[j]));
      }
      P.bw[g][ks] = f;
    }
  }
}

// One LSTM cell step for 32 rows (two 16-row m-halves, independent accumulators).
// h read from hsh[cur] (single fp16 plane), x from xsrc[32][2] (only when HASX),
// new h written to hsh[cur^1]. c per-lane fp32. One LDS-only barrier.
template<bool HASX>
__device__ __forceinline__ void cell_step(_Float16 (*hsh)[M][HP], int cur,
                                          const float* __restrict__ xsrc,
                                          const PhaseConsts& P, float (&c)[2][4],
                                          int wv, int l15, int q){
  float4_t acc[2][4];
  if constexpr (HASX){
#pragma unroll
    for(int mh=0; mh<2; mh++){
      float x0[4], x1[4];
#pragma unroll
      for(int r=0; r<4; r++){
        x0[r] = xsrc[(mh*16 + 4*q+r)*2 + 0];
        x1[r] = xsrc[(mh*16 + 4*q+r)*2 + 1];
      }
#pragma unroll
      for(int g=0; g<4; g++)
#pragma unroll
        for(int r=0; r<4; r++)
          acc[mh][g][r] = fmaf(P.w1[g], x1[r], fmaf(P.w0[g], x0[r], P.bs[g]));
    }
  } else {
#pragma unroll
    for(int mh=0; mh<2; mh++)
#pragma unroll
      for(int g=0; g<4; g++)
#pragma unroll
        for(int r=0; r<4; r++)
          acc[mh][g][r] = P.bs[g];
  }

#pragma unroll
  for(int ks=0; ks<4; ks++){
#pragma unroll
    for(int mh=0; mh<2; mh++){
      const half8_t a = *(const half8_t*)&hsh[cur][mh*16 + l15][ks*32 + q*8];
#pragma unroll
      for(int g=0; g<4; g++){
        acc[mh][g] = __builtin_amdgcn_mfma_f32_16x16x32_f16(a, P.bw[g][ks], acc[mh][g], 0,0,0);
      }
    }
  }
  const int nxt = cur ^ 1;
  const int u = 16*wv + l15;
#pragma unroll
  for(int mh=0; mh<2; mh++){
#pragma unroll
    for(int r=0; r<4; r++){
      const float iv = sig_f(acc[mh][0][r]);
      const float fv = sig_f(acc[mh][1][r]);
      const float gv = tanh_f(acc[mh][2][r]);
      const float ov = sig_f(acc[mh][3][r]);
      const float cc = fmaf(fv, c[mh][r], iv*gv);
      c[mh][r] = cc;
      const float hv = ov * tanh_f(cc);
      const int m = mh*16 + 4*q + r;
      hsh[nxt][m][u] = (_Float16)hv;
    }
  }
  lds_barrier();
}

// LayerNorm over 128 units for 32 rows; all 512 threads, 16 threads/row.
__device__ __forceinline__ void layernorm32(const float (*src)[FP], float (*dst)[FP],
                                            const float* __restrict__ g,
                                            const float* __restrict__ b, int tid){
  const int m = tid >> 4, sub = tid & 15;
  float v[8];
  float s = 0.f, s2 = 0.f;
#pragma unroll
  for(int j=0;j<8;j++){ v[j] = src[m][sub*8+j]; s += v[j]; s2 = fmaf(v[j], v[j], s2); }
#pragma unroll
  for(int msk=1; msk<16; msk<<=1){ s += __shfl_xor(s, msk, 64); s2 += __shfl_xor(s2, msk, 64); }
  const float mean = s * (1.f/H);
  const float var  = fmaf(-mean, mean, s2 * (1.f/H));   // PINNED contraction
  const float inv  = rsqrtf(var + LN_EPS);
#pragma unroll
  for(int j=0;j<8;j++){
    const int u = sub*8+j;
    dst[m][u] = fmaf((v[j]-mean)*inv, g[u], b[u]);
  }
}

// Output-only FC: cs = h @ Wfc^T + bfc from the fp16 plane; writes global out ONLY.
// No barrier needed: hb rewritten two cell-steps later (barrier in between).
__device__ __forceinline__ void fc_out(const _Float16 (*hb)[HP], const float (*wfc)[H],
                                       const float* __restrict__ bfcs,
                                       float* __restrict__ gout, int row0, int tid){
  const int m = tid >> 4, d = (tid >> 3) & 1, ch = tid & 7;
  const _Float16* hp = &hb[m][ch*16];
  float s = 0.f;
#pragma unroll
  for(int j=0;j<16;j++) s = fmaf((float)hp[j], wfc[d][ch*16+j], s);
  s += __shfl_xor(s, 1, 64); s += __shfl_xor(s, 2, 64); s += __shfl_xor(s, 4, 64);
  if(ch == 0){
    gout[(size_t)(row0+m)*D + d] = s + bfcs[d];
  }
}

// Step-0 delta: xb[m][d] = xlast[m][d] - (Wfc@h0 + bfc)[m][d]. All 512 threads.
__device__ __forceinline__ void fc_delta(const _Float16 (*hb)[HP], const float (*wfc)[H],
                                         const float* __restrict__ bfcs,
                                         const float* __restrict__ xlast,  // [M][D] contiguous
                                         float (*xb)[D], int tid){
  const int m = tid >> 4, d = (tid >> 3) & 1, ch = tid & 7;
  const _Float16* hp = &hb[m][ch*16];
  float s = 0.f;
#pragma unroll
  for(int j=0;j<16;j++) s = fmaf((float)hp[j], wfc[d][ch*16+j], s);
  s += __shfl_xor(s, 1, 64); s += __shfl_xor(s, 2, 64); s += __shfl_xor(s, 4, 64);
  if(ch == 0){
    xb[m][d] = xlast[m*D + d] - (s + bfcs[d]);
  }
}

__global__ __launch_bounds__(NTH, 2) void traj_kernel(
    const float* __restrict__ pos, const float* __restrict__ speed,
    const float* __restrict__ Wih_pe, const float* __restrict__ Whh_pe,
    const float* __restrict__ bih_pe, const float* __restrict__ bhh_pe,
    const float* __restrict__ Wih_se, const float* __restrict__ Whh_se,
    const float* __restrict__ bih_se, const float* __restrict__ bhh_se,
    const float* __restrict__ ln_g, const float* __restrict__ ln_b,
    const float* __restrict__ Wih_sd, const float* __restrict__ Whh_sd,
    const float* __restrict__ bih_sd, const float* __restrict__ bhh_sd,
    const float* __restrict__ Wih_pd, const float* __restrict__ Whh_pd,
    const float* __restrict__ bih_pd, const float* __restrict__ bhh_pd,
    const float* __restrict__ Wfc, const float* __restrict__ bfc,
    float* __restrict__ out)
{
  __shared__ __align__(16) _Float16 hsh[2][M][HP];    // [buf][m][u]  ~17.4 KB
  __shared__ float tmpf[M][FP];                        // ~16.9 KB each
  __shared__ float hpoN[M][FP];
  __shared__ float cpoN[M][FP];
  __shared__ float seqx[2][T_OBS][M][D];               // ~10.2 KB
  __shared__ float xbuf[M][D];
  __shared__ float wfcs[D][H];
  __shared__ float bfcs[2];
  // total ~79.6 KB

  const int tid  = threadIdx.x;
  const int lane = tid & 63;
  const int wv   = tid >> 6;       // 0..7 -> unit group
  const int q    = lane >> 4;
  const int l15  = lane & 15;
  const int row0 = blockIdx.x * M;
  const int u    = 16*wv + l15;

  // ---- stage inputs ----
  for(int idx = tid; idx < 2*T_OBS*M*D; idx += NTH){
    const int chain = idx / (T_OBS*M*D);
    const int rem   = idx % (T_OBS*M*D);
    const int t = rem / (M*D), e = rem % (M*D);
    const float* src = chain ? speed : pos;
    seqx[chain][t][e>>1][e&1] = src[(size_t)t*BATCH*D + row0*D + e];
  }
  if(tid < D*H) wfcs[tid>>7][tid&127] = Wfc[tid];
  if(tid < 2)   bfcs[tid] = bfc[tid];
  { int* hz = (int*)&hsh[0][0][0];                    // zero buf0 (M*HP fp16 = 2176 ints)
    for(int idx = tid; idx < M*HP/2; idx += NTH) hz[idx] = 0; }

  PhaseConsts P;
  float c[2][4];
  load_phase(P, Whh_pe, Wih_pe, bih_pe, bhh_pe, wv, l15, q);
#pragma unroll
  for(int mh=0;mh<2;mh++)
#pragma unroll
    for(int r=0;r<4;r++) c[mh][r] = 0.f;
  __syncthreads();

  // ---------- phase 1: pos encoder ----------
  int cur = 0;
  for(int t=0; t<T_OBS; t++){ cell_step<true>(hsh, cur, &seqx[0][t][0][0], P, c, wv, l15, q); cur ^= 1; }
  for(int idx=tid; idx<M*H; idx+=NTH){
    const int m = idx>>7, uu = idx&127;
    tmpf[m][uu] = (float)hsh[cur][m][uu];
  }
  __syncthreads();
  layernorm32(tmpf, hpoN, ln_g, ln_b, tid);
  __syncthreads();
#pragma unroll
  for(int mh=0;mh<2;mh++)
#pragma unroll
    for(int r=0;r<4;r++) tmpf[mh*16 + 4*q+r][u] = c[mh][r];
  __syncthreads();
  layernorm32(tmpf, cpoN, ln_g, ln_b, tid);
  __syncthreads();

  // ---------- phase 2: speed encoder ----------
  load_phase(P, Whh_se, Wih_se, bih_se, bhh_se, wv, l15, q);
#pragma unroll
  for(int mh=0;mh<2;mh++)
#pragma unroll
    for(int r=0;r<4;r++) c[mh][r] = 0.f;
  for(int idx=tid; idx<M*H; idx+=NTH){
    const int m = idx>>7, uu = idx&127;
    hsh[0][m][uu] = (_Float16)0.f;
  }
  cur = 0;
  __syncthreads();
  for(int t=0; t<T_OBS; t++){ cell_step<true>(hsh, cur, &seqx[1][t][0][0], P, c, wv, l15, q); cur ^= 1; }
  for(int idx=tid; idx<M*H; idx+=NTH){
    const int m = idx>>7, uu = idx&127;
    tmpf[m][uu] = (float)hsh[cur][m][uu];
  }
  __syncthreads();
  layernorm32(tmpf, tmpf, ln_g, ln_b, tid);
  __syncthreads();
  // hds = LN(hsp) + LN(hpo) -> hsh[0]
  for(int idx=tid; idx<M*H; idx+=NTH){
    const int m = idx>>7, uu = idx&127;
    hsh[0][m][uu] = (_Float16)(tmpf[m][uu] + hpoN[m][uu]);
  }
  __syncthreads();
  // cds = LN(csp) + LN(cpo)
#pragma unroll
  for(int mh=0;mh<2;mh++)
#pragma unroll
    for(int r=0;r<4;r++) tmpf[mh*16 + 4*q+r][u] = c[mh][r];
  __syncthreads();
  layernorm32(tmpf, tmpf, ln_g, ln_b, tid);
  __syncthreads();
#pragma unroll
  for(int mh=0;mh<2;mh++)
#pragma unroll
    for(int r=0;r<4;r++) c[mh][r] = tmpf[mh*16 + 4*q+r][u] + cpoN[mh*16 + 4*q+r][u];

  // ---------- phase 3: speed decoder (FC folded into recurrence) ----------
  load_phase_dec(P, Whh_sd, Wih_sd, bih_sd, bhh_sd, Wfc, bfc, wv, l15, q);
  // dx = x0 - (Wfc@h0 + bfc); h0 = hds already in hsh[0] (visible: barrier above)
  fc_delta(hsh[0], wfcs, bfcs, &seqx[1][T_OBS-1][0][0], xbuf, tid);
  __syncthreads();

  float* spd_out = out + (size_t)PRED*BATCH*D;
  cur = 0;
  cell_step<true>(hsh, cur, &xbuf[0][0], P, c, wv, l15, q);
  fc_out(hsh[cur^1], wfcs, bfcs, spd_out, row0, tid);
  cur ^= 1;
  for(int t=1; t<PRED; t++){
    cell_step<false>(hsh, cur, nullptr, P, c, wv, l15, q);
    fc_out(hsh[cur^1], wfcs, bfcs, spd_out + (size_t)t*BATCH*D, row0, tid);
    cur ^= 1;
  }
  __syncthreads();   // protect hsh buffer still being read by last fc_out before reuse

  // ---------- phase 4: pos decoder ----------
  for(int idx=tid; idx<M*H; idx+=NTH){
    const int m = idx>>7, uu = idx&127;
    hsh[0][m][uu] = (_Float16)hpoN[m][uu];
  }
#pragma unroll
  for(int mh=0;mh<2;mh++)
#pragma unroll
    for(int r=0;r<4;r++) c[mh][r] = cpoN[mh*16 + 4*q+r][u];
  load_phase_dec(P, Whh_pd, Wih_pd, bih_pd, bhh_pd, Wfc, bfc, wv, l15, q);
  __syncthreads();   // hsh[0] (h0 = LN(hpo)) visible
  fc_delta(hsh[0], wfcs, bfcs, &seqx[0][T_OBS-1][0][0], xbuf, tid);
  __syncthreads();   // xbuf visible

  cur = 0;
  cell_step<true>(hsh, cur, &xbuf[0][0], P, c, wv, l15, q);
  fc_out(hsh[cur^1], wfcs, bfcs, out, row0, tid);
  cur ^= 1;
  for(int t=1; t<PRED; t++){
    cell_step<false>(hsh, cur, nullptr, P, c, wv, l15, q);
    fc_out(hsh[cur^1], wfcs, bfcs, out + (size_t)t*BATCH*D, row0, tid);
    cur ^= 1;
  }
}

extern "C" void kernel_launch(void* const* d_in, const int* in_sizes, int n_in,
                              void* d_out, int out_size, void* d_ws, size_t ws_size,
                              hipStream_t stream)
{
  const float* pos    = (const float*)d_in[0];
  const float* speed  = (const float*)d_in[1];
  const float* Wih_pe = (const float*)d_in[2];
  const float* Whh_pe = (const float*)d_in[3];
  const float* bih_pe = (const float*)d_in[4];
  const float* bhh_pe = (const float*)d_in[5];
  const float* Wih_se = (const float*)d_in[6];
  const float* Whh_se = (const float*)d_in[7];
  const float* bih_se = (const float*)d_in[8];
  const float* bhh_se = (const float*)d_in[9];
  const float* ln_g   = (const float*)d_in[10];
  const float* ln_b   = (const float*)d_in[11];
  const float* Wih_sd = (const float*)d_in[12];
  const float* Whh_sd = (const float*)d_in[13];
  const float* bih_sd = (const float*)d_in[14];
  const float* bhh_sd = (const float*)d_in[15];
  const float* Wih_pd = (const float*)d_in[16];
  const float* Whh_pd = (const float*)d_in[17];
  const float* bih_pd = (const float*)d_in[18];
  const float* bhh_pd = (const float*)d_in[19];
  const float* Wfc    = (const float*)d_in[20];
  const float* bfc    = (const float*)d_in[21];

  traj_kernel<<<BATCH/M, NTH, 0, stream>>>(
      pos, speed, Wih_pe, Whh_pe, bih_pe, bhh_pe,
      Wih_se, Whh_se, bih_se, bhh_se, ln_g, ln_b,
      Wih_sd, Whh_sd, bih_sd, bhh_sd, Wih_pd, Whh_pd, bih_pd, bhh_pd,
      Wfc, bfc, (float*)d_out);
}

// Round 15
// 506.656 us; speedup vs baseline: 1.6707x; 1.0786x over previous
//
#include <hip/hip_runtime.h>

#define H 128
#define D 2
#define T_OBS 20
#define BATCH 16384
#define PRED 30
#define M 32          // batch rows per block (two 16-row MFMA tiles)
#define NTH 512       // 8 waves; wave wv owns units 16*wv .. 16*wv+15 (all 4 gates)
#define HP 136        // padded fp16 h-row stride
#define FP 132        // padded f32 row stride
#define LN_EPS 1e-5f
#define LOG2E  1.442695041f
#define LOG2E2 2.885390082f   // 2*log2e

typedef __attribute__((ext_vector_type(8))) _Float16 half8_t;
typedef __attribute__((ext_vector_type(2))) _Float16 half2_t;
typedef __attribute__((ext_vector_type(4))) float float4_t;

__device__ __forceinline__ float fast_rcp(float x){ return __builtin_amdgcn_rcpf(x); }
__device__ __forceinline__ float exp2_f(float x){ return __builtin_amdgcn_exp2f(x); }
// PRE-SCALED gate math: weights folded with log2e so no argument mul is needed.
// sig2(a)  = sigmoid(x)  where a = log2e*x   : 1/(1+2^-a)
// th2(a)   = tanh(x)     where a = 2*log2e*x : 1 - 2/(2^a+1)
// th_cc(c) = tanh(c)     (c in natural units; one mul remains)
__device__ __forceinline__ float sig2(float a){ return fast_rcp(1.f + exp2_f(-a)); }
__device__ __forceinline__ float th2(float a){ return fmaf(-2.f, fast_rcp(exp2_f(a)+1.f), 1.f); }
__device__ __forceinline__ float th_cc(float c){ return fmaf(-2.f, fast_rcp(exp2_f(c*LOG2E2)+1.f), 1.f); }

// LDS-only barrier: __syncthreads() emits s_waitcnt vmcnt(0) lgkmcnt(0); the
// vmcnt(0) forces each decoder step to drain fc_out's global stores (write-only,
// never re-read -> pure stall). All inter-wave communication in the step loop is
// through LDS; lgkmcnt(0) covers it. [R14: verified correct + faster]
__device__ __forceinline__ void lds_barrier(){
  asm volatile("s_waitcnt lgkmcnt(0)\n\ts_barrier" ::: "memory");
}

// Per-phase per-wave constants: bw 64 VGPR + consts 12; acc 32 AGPR.
// (512,2) is the ONLY non-spilling envelope (R7/R8/R11/R12/R13).
struct PhaseConsts {
  half8_t bw[4][4];
  float bs[4], w0[4], w1[4];
};

__device__ __forceinline__ void load_phase(PhaseConsts& P, const float* __restrict__ Whh,
                                           const float* __restrict__ Wih,
                                           const float* __restrict__ bih,
                                           const float* __restrict__ bhh,
                                           int wv, int l15, int q){
#pragma unroll
  for(int g=0; g<4; g++){
    const float sc = (g==2) ? LOG2E2 : LOG2E;   // fold exp's log2e into weights
    const int n = g*H + 16*wv + l15;
    P.bs[g] = (bih[n] + bhh[n]) * sc;
    P.w0[g] = Wih[n*D + 0] * sc;
    P.w1[g] = Wih[n*D + 1] * sc;
#pragma unroll
    for(int ks=0; ks<4; ks++){
      const float* p = Whh + (size_t)n*H + ks*32 + q*8;  // B[k][n]=Whh[n][k]
      float4 a = *(const float4*)p;
      float4 b = *(const float4*)(p+4);
      half8_t f;
      f[0]=(_Float16)(a.x*sc); f[1]=(_Float16)(a.y*sc); f[2]=(_Float16)(a.z*sc); f[3]=(_Float16)(a.w*sc);
      f[4]=(_Float16)(b.x*sc); f[5]=(_Float16)(b.y*sc); f[6]=(_Float16)(b.z*sc); f[7]=(_Float16)(b.w*sc);
      P.bw[g][ks] = f;
    }
  }
}

// Decoder fold: Wcomb = Whh + Wih*Wfc, b' = b + Wih*bfc, then *sc.
// PINNED: explicit fmaf, deterministic (4-for-4 at 1 bf16 ulp: R11-R14).
__device__ __forceinline__ void load_phase_dec(PhaseConsts& P, const float* __restrict__ Whh,
                                               const float* __restrict__ Wih,
                                               const float* __restrict__ bih,
                                               const float* __restrict__ bhh,
                                               const float* __restrict__ Wfc,
                                               const float* __restrict__ bfc,
                                               int wv, int l15, int q){
#pragma unroll
  for(int g=0; g<4; g++){
    const float sc = (g==2) ? LOG2E2 : LOG2E;
    const int n = g*H + 16*wv + l15;
    const float wi0 = Wih[n*D + 0];
    const float wi1 = Wih[n*D + 1];
    P.bs[g] = fmaf(wi1, bfc[1], fmaf(wi0, bfc[0], bih[n] + bhh[n])) * sc;
    P.w0[g] = wi0 * sc;
    P.w1[g] = wi1 * sc;
#pragma unroll
    for(int ks=0; ks<4; ks++){
      const float* p  = Whh + (size_t)n*H + ks*32 + q*8;
      const float* f0 = Wfc + 0*H + ks*32 + q*8;
      const float* f1 = Wfc + 1*H + ks*32 + q*8;
      half8_t f;
#pragma unroll
      for(int j=0;j<8;j++){
        f[j] = (_Float16)(fmaf(wi1, f1[j], fmaf(wi0, f0[j], p[j])) * sc);
      }
      P.bw[g][ks] = f;
    }
  }
}

// One LSTM cell step for 32 rows (two 16-row m-halves, independent accumulators).
// h read from hsh[cur] (single fp16 plane), x from xsrc[32][2] (only when HASX),
// new h written to hsh[cur^1]. c per-lane fp32. One LDS-only barrier.
// acc values are PRE-SCALED gate args (log2e folded in weights).
template<bool HASX>
__device__ __forceinline__ void cell_step(_Float16 (*hsh)[M][HP], int cur,
                                          const float* __restrict__ xsrc,
                                          const PhaseConsts& P, float (&c)[2][4],
                                          int wv, int l15, int q){
  float4_t acc[2][4];
  if constexpr (HASX){
#pragma unroll
    for(int mh=0; mh<2; mh++){
      float x0[4], x1[4];
#pragma unroll
      for(int r=0; r<4; r++){
        x0[r] = xsrc[(mh*16 + 4*q+r)*2 + 0];
        x1[r] = xsrc[(mh*16 + 4*q+r)*2 + 1];
      }
#pragma unroll
      for(int g=0; g<4; g++)
#pragma unroll
        for(int r=0; r<4; r++)
          acc[mh][g][r] = fmaf(P.w1[g], x1[r], fmaf(P.w0[g], x0[r], P.bs[g]));
    }
  } else {
#pragma unroll
    for(int mh=0; mh<2; mh++)
#pragma unroll
      for(int g=0; g<4; g++)
#pragma unroll
        for(int r=0; r<4; r++)
          acc[mh][g][r] = P.bs[g];
  }

#pragma unroll
  for(int ks=0; ks<4; ks++){
#pragma unroll
    for(int mh=0; mh<2; mh++){
      const half8_t a = *(const half8_t*)&hsh[cur][mh*16 + l15][ks*32 + q*8];
#pragma unroll
      for(int g=0; g<4; g++){
        acc[mh][g] = __builtin_amdgcn_mfma_f32_16x16x32_f16(a, P.bw[g][ks], acc[mh][g], 0,0,0);
      }
    }
  }
  const int nxt = cur ^ 1;
  const int u = 16*wv + l15;
#pragma unroll
  for(int mh=0; mh<2; mh++){
#pragma unroll
    for(int r=0; r<4; r++){
      const float iv = sig2(acc[mh][0][r]);
      const float fv = sig2(acc[mh][1][r]);
      const float gv = th2(acc[mh][2][r]);
      const float ov = sig2(acc[mh][3][r]);
      const float cc = fmaf(fv, c[mh][r], iv*gv);
      c[mh][r] = cc;
      const float hv = ov * th_cc(cc);
      const int m = mh*16 + 4*q + r;
      hsh[nxt][m][u] = (_Float16)hv;
    }
  }
  lds_barrier();
}

// LayerNorm over 128 units for 32 rows; all 512 threads, 16 threads/row.
__device__ __forceinline__ void layernorm32(const float (*src)[FP], float (*dst)[FP],
                                            const float* __restrict__ g,
                                            const float* __restrict__ b, int tid){
  const int m = tid >> 4, sub = tid & 15;
  float v[8];
  float s = 0.f, s2 = 0.f;
#pragma unroll
  for(int j=0;j<8;j++){ v[j] = src[m][sub*8+j]; s += v[j]; s2 = fmaf(v[j], v[j], s2); }
#pragma unroll
  for(int msk=1; msk<16; msk<<=1){ s += __shfl_xor(s, msk, 64); s2 += __shfl_xor(s2, msk, 64); }
  const float mean = s * (1.f/H);
  const float var  = fmaf(-mean, mean, s2 * (1.f/H));   // PINNED contraction
  const float inv  = rsqrtf(var + LN_EPS);
#pragma unroll
  for(int j=0;j<8;j++){
    const int u = sub*8+j;
    dst[m][u] = fmaf((v[j]-mean)*inv, g[u], b[u]);
  }
}

// Output-only FC via v_dot2_f32_f16: cs = h @ Wfc^T + bfc, fp16 Wfc copy.
// Writes global out ONLY (never feeds the recurrence) -> fp16 Wfc quantization
// perturbs outputs by < 1/2 bf16 ulp, recurrence untouched.
// No barrier needed: hb rewritten two cell-steps later (barrier in between).
__device__ __forceinline__ void fc_out(const _Float16 (*hb)[HP], const _Float16 (*wfch)[H],
                                       const float* __restrict__ bfcs,
                                       float* __restrict__ gout, int row0, int tid){
  const int m = tid >> 4, d = (tid >> 3) & 1, ch = tid & 7;
  const half2_t* hp2 = (const half2_t*)&hb[m][ch*16];
  const half2_t* wp2 = (const half2_t*)&wfch[d][ch*16];
  float s = 0.f;
#pragma unroll
  for(int j=0;j<8;j++) s = __builtin_amdgcn_fdot2(hp2[j], wp2[j], s, false);
  s += __shfl_xor(s, 1, 64); s += __shfl_xor(s, 2, 64); s += __shfl_xor(s, 4, 64);
  if(ch == 0){
    gout[(size_t)(row0+m)*D + d] = s + bfcs[d];
  }
}

// Step-0 delta: xb[m][d] = xlast[m][d] - (Wfc@h0 + bfc)[m][d]. All 512 threads.
// KEEPS the f32 Wfc path: this feeds the decoder recurrence (draw-sensitive).
__device__ __forceinline__ void fc_delta(const _Float16 (*hb)[HP], const float (*wfc)[H],
                                         const float* __restrict__ bfcs,
                                         const float* __restrict__ xlast,  // [M][D] contiguous
                                         float (*xb)[D], int tid){
  const int m = tid >> 4, d = (tid >> 3) & 1, ch = tid & 7;
  const _Float16* hp = &hb[m][ch*16];
  float s = 0.f;
#pragma unroll
  for(int j=0;j<16;j++) s = fmaf((float)hp[j], wfc[d][ch*16+j], s);
  s += __shfl_xor(s, 1, 64); s += __shfl_xor(s, 2, 64); s += __shfl_xor(s, 4, 64);
  if(ch == 0){
    xb[m][d] = xlast[m*D + d] - (s + bfcs[d]);
  }
}

__global__ __launch_bounds__(NTH, 2) void traj_kernel(
    const float* __restrict__ pos, const float* __restrict__ speed,
    const float* __restrict__ Wih_pe, const float* __restrict__ Whh_pe,
    const float* __restrict__ bih_pe, const float* __restrict__ bhh_pe,
    const float* __restrict__ Wih_se, const float* __restrict__ Whh_se,
    const float* __restrict__ bih_se, const float* __restrict__ bhh_se,
    const float* __restrict__ ln_g, const float* __restrict__ ln_b,
    const float* __restrict__ Wih_sd, const float* __restrict__ Whh_sd,
    const float* __restrict__ bih_sd, const float* __restrict__ bhh_sd,
    const float* __restrict__ Wih_pd, const float* __restrict__ Whh_pd,
    const float* __restrict__ bih_pd, const float* __restrict__ bhh_pd,
    const float* __restrict__ Wfc, const float* __restrict__ bfc,
    float* __restrict__ out)
{
  __shared__ __align__(16) _Float16 hsh[2][M][HP];    // [buf][m][u]  ~17.4 KB
  __shared__ float tmpf[M][FP];                        // ~16.9 KB each
  __shared__ float hpoN[M][FP];
  __shared__ float cpoN[M][FP];
  __shared__ float seqx[2][T_OBS][M][D];               // ~10.2 KB
  __shared__ float xbuf[M][D];
  __shared__ float wfcs[D][H];
  __shared__ __align__(16) _Float16 wfch[D][H];        // fp16 Wfc for fc_out dot2
  __shared__ float bfcs[2];
  // total ~80.1 KB

  const int tid  = threadIdx.x;
  const int lane = tid & 63;
  const int wv   = tid >> 6;       // 0..7 -> unit group
  const int q    = lane >> 4;
  const int l15  = lane & 15;
  const int row0 = blockIdx.x * M;
  const int u    = 16*wv + l15;

  // ---- stage inputs ----
  for(int idx = tid; idx < 2*T_OBS*M*D; idx += NTH){
    const int chain = idx / (T_OBS*M*D);
    const int rem   = idx % (T_OBS*M*D);
    const int t = rem / (M*D), e = rem % (M*D);
    const float* src = chain ? speed : pos;
    seqx[chain][t][e>>1][e&1] = src[(size_t)t*BATCH*D + row0*D + e];
  }
  if(tid < D*H){
    wfcs[tid>>7][tid&127] = Wfc[tid];
    wfch[tid>>7][tid&127] = (_Float16)Wfc[tid];
  }
  if(tid < 2)   bfcs[tid] = bfc[tid];
  { int* hz = (int*)&hsh[0][0][0];                    // zero buf0 (M*HP fp16 = 2176 ints)
    for(int idx = tid; idx < M*HP/2; idx += NTH) hz[idx] = 0; }

  PhaseConsts P;
  float c[2][4];
  load_phase(P, Whh_pe, Wih_pe, bih_pe, bhh_pe, wv, l15, q);
#pragma unroll
  for(int mh=0;mh<2;mh++)
#pragma unroll
    for(int r=0;r<4;r++) c[mh][r] = 0.f;
  __syncthreads();

  // ---------- phase 1: pos encoder ----------
  int cur = 0;
  for(int t=0; t<T_OBS; t++){ cell_step<true>(hsh, cur, &seqx[0][t][0][0], P, c, wv, l15, q); cur ^= 1; }
  for(int idx=tid; idx<M*H; idx+=NTH){
    const int m = idx>>7, uu = idx&127;
    tmpf[m][uu] = (float)hsh[cur][m][uu];
  }
  __syncthreads();
  layernorm32(tmpf, hpoN, ln_g, ln_b, tid);
  __syncthreads();
#pragma unroll
  for(int mh=0;mh<2;mh++)
#pragma unroll
    for(int r=0;r<4;r++) tmpf[mh*16 + 4*q+r][u] = c[mh][r];
  __syncthreads();
  layernorm32(tmpf, cpoN, ln_g, ln_b, tid);
  __syncthreads();

  // ---------- phase 2: speed encoder ----------
  load_phase(P, Whh_se, Wih_se, bih_se, bhh_se, wv, l15, q);
#pragma unroll
  for(int mh=0;mh<2;mh++)
#pragma unroll
    for(int r=0;r<4;r++) c[mh][r] = 0.f;
  for(int idx=tid; idx<M*H; idx+=NTH){
    const int m = idx>>7, uu = idx&127;
    hsh[0][m][uu] = (_Float16)0.f;
  }
  cur = 0;
  __syncthreads();
  for(int t=0; t<T_OBS; t++){ cell_step<true>(hsh, cur, &seqx[1][t][0][0], P, c, wv, l15, q); cur ^= 1; }
  for(int idx=tid; idx<M*H; idx+=NTH){
    const int m = idx>>7, uu = idx&127;
    tmpf[m][uu] = (float)hsh[cur][m][uu];
  }
  __syncthreads();
  layernorm32(tmpf, tmpf, ln_g, ln_b, tid);
  __syncthreads();
  // hds = LN(hsp) + LN(hpo) -> hsh[0]
  for(int idx=tid; idx<M*H; idx+=NTH){
    const int m = idx>>7, uu = idx&127;
    hsh[0][m][uu] = (_Float16)(tmpf[m][uu] + hpoN[m][uu]);
  }
  __syncthreads();
  // cds = LN(csp) + LN(cpo)
#pragma unroll
  for(int mh=0;mh<2;mh++)
#pragma unroll
    for(int r=0;r<4;r++) tmpf[mh*16 + 4*q+r][u] = c[mh][r];
  __syncthreads();
  layernorm32(tmpf, tmpf, ln_g, ln_b, tid);
  __syncthreads();
#pragma unroll
  for(int mh=0;mh<2;mh++)
#pragma unroll
    for(int r=0;r<4;r++) c[mh][r] = tmpf[mh*16 + 4*q+r][u] + cpoN[mh*16 + 4*q+r][u];

  // ---------- phase 3: speed decoder (FC folded into recurrence) ----------
  load_phase_dec(P, Whh_sd, Wih_sd, bih_sd, bhh_sd, Wfc, bfc, wv, l15, q);
  // dx = x0 - (Wfc@h0 + bfc); h0 = hds already in hsh[0] (visible: barrier above)
  fc_delta(hsh[0], wfcs, bfcs, &seqx[1][T_OBS-1][0][0], xbuf, tid);
  __syncthreads();

  float* spd_out = out + (size_t)PRED*BATCH*D;
  cur = 0;
  cell_step<true>(hsh, cur, &xbuf[0][0], P, c, wv, l15, q);
  fc_out(hsh[cur^1], wfch, bfcs, spd_out, row0, tid);
  cur ^= 1;
  for(int t=1; t<PRED; t++){
    cell_step<false>(hsh, cur, nullptr, P, c, wv, l15, q);
    fc_out(hsh[cur^1], wfch, bfcs, spd_out + (size_t)t*BATCH*D, row0, tid);
    cur ^= 1;
  }
  __syncthreads();   // protect hsh buffer still being read by last fc_out before reuse

  // ---------- phase 4: pos decoder ----------
  for(int idx=tid; idx<M*H; idx+=NTH){
    const int m = idx>>7, uu = idx&127;
    hsh[0][m][uu] = (_Float16)hpoN[m][uu];
  }
#pragma unroll
  for(int mh=0;mh<2;mh++)
#pragma unroll
    for(int r=0;r<4;r++) c[mh][r] = cpoN[mh*16 + 4*q+r][u];
  load_phase_dec(P, Whh_pd, Wih_pd, bih_pd, bhh_pd, Wfc, bfc, wv, l15, q);
  __syncthreads();   // hsh[0] (h0 = LN(hpo)) visible
  fc_delta(hsh[0], wfcs, bfcs, &seqx[0][T_OBS-1][0][0], xbuf, tid);
  __syncthreads();   // xbuf visible

  cur = 0;
  cell_step<true>(hsh, cur, &xbuf[0][0], P, c, wv, l15, q);
  fc_out(hsh[cur^1], wfch, bfcs, out, row0, tid);
  cur ^= 1;
  for(int t=1; t<PRED; t++){
    cell_step<false>(hsh, cur, nullptr, P, c, wv, l15, q);
    fc_out(hsh[cur^1], wfch, bfcs, out + (size_t)t*BATCH*D, row0, tid);
    cur ^= 1;
  }
}

extern "C" void kernel_launch(void* const* d_in, const int* in_sizes, int n_in,
                              void* d_out, int out_size, void* d_ws, size_t ws_size,
                              hipStream_t stream)
{
  const float* pos    = (const float*)d_in[0];
  const float* speed  = (const float*)d_in[1];
  const float* Wih_pe = (const float*)d_in[2];
  const float* Whh_pe = (const float*)d_in[3];
  const float* bih_pe = (const float*)d_in[4];
  const float* bhh_pe = (const float*)d_in[5];
  const float* Wih_se = (const float*)d_in[6];
  const float* Whh_se = (const float*)d_in[7];
  const float* bih_se = (const float*)d_in[8];
  const float* bhh_se = (const float*)d_in[9];
  const float* ln_g   = (const float*)d_in[10];
  const float* ln_b   = (const float*)d_in[11];
  const float* Wih_sd = (const float*)d_in[12];
  const float* Whh_sd = (const float*)d_in[13];
  const float* bih_sd = (const float*)d_in[14];
  const float* bhh_sd = (const float*)d_in[15];
  const float* Wih_pd = (const float*)d_in[16];
  const float* Whh_pd = (const float*)d_in[17];
  const float* bih_pd = (const float*)d_in[18];
  const float* bhh_pd = (const float*)d_in[19];
  const float* Wfc    = (const float*)d_in[20];
  const float* bfc    = (const float*)d_in[21];

  traj_kernel<<<BATCH/M, NTH, 0, stream>>>(
      pos, speed, Wih_pe, Whh_pe, bih_pe, bhh_pe,
      Wih_se, Whh_se, bih_se, bhh_se, ln_g, ln_b,
      Wih_sd, Whh_sd, bih_sd, bhh_sd, Wih_pd, Whh_pd, bih_pd, bhh_pd,
      Wfc, bfc, (float*)d_out);
}

// Round 16
// 497.448 us; speedup vs baseline: 1.7016x; 1.0185x over previous
//
#include <hip/hip_runtime.h>

#define H 128
#define D 2
#define T_OBS 20
#define BATCH 16384
#define PRED 30
#define M 32          // batch rows per block (two 16-row MFMA tiles)
#define NTH 512       // 8 waves; wave wv owns units 16*wv .. 16*wv+15 (all 4 gates)
#define HP 136        // padded fp16 h-row stride
#define FP 132        // padded f32 row stride
#define LN_EPS 1e-5f
#define LOG2E  1.442695041f
#define LOG2E2 2.885390082f   // 2*log2e

typedef __attribute__((ext_vector_type(8))) _Float16 half8_t;
typedef __attribute__((ext_vector_type(2))) _Float16 half2_t;
typedef __attribute__((ext_vector_type(4))) float float4_t;

__device__ __forceinline__ float fast_rcp(float x){ return __builtin_amdgcn_rcpf(x); }
__device__ __forceinline__ float exp2_f(float x){ return __builtin_amdgcn_exp2f(x); }

// LDS-only barrier: __syncthreads() emits s_waitcnt vmcnt(0) lgkmcnt(0); the
// vmcnt(0) forces each decoder step to drain fc_out's global stores (write-only,
// never re-read -> pure stall). All inter-wave communication in the step loop is
// through LDS; lgkmcnt(0) covers it. [R14: verified correct + faster]
__device__ __forceinline__ void lds_barrier(){
  asm volatile("s_waitcnt lgkmcnt(0)\n\ts_barrier" ::: "memory");
}

// Per-phase per-wave constants: bw 64 VGPR + consts 12; acc 32 AGPR.
// (512,2) is the ONLY non-spilling envelope (R7/R8/R11/R12/R13).
struct PhaseConsts {
  half8_t bw[4][4];
  float bs[4], w0[4], w1[4];
};

__device__ __forceinline__ void load_phase(PhaseConsts& P, const float* __restrict__ Whh,
                                           const float* __restrict__ Wih,
                                           const float* __restrict__ bih,
                                           const float* __restrict__ bhh,
                                           int wv, int l15, int q){
#pragma unroll
  for(int g=0; g<4; g++){
    const float sc = (g==2) ? LOG2E2 : LOG2E;   // fold exp's log2e into weights
    const int n = g*H + 16*wv + l15;
    P.bs[g] = (bih[n] + bhh[n]) * sc;
    P.w0[g] = Wih[n*D + 0] * sc;
    P.w1[g] = Wih[n*D + 1] * sc;
#pragma unroll
    for(int ks=0; ks<4; ks++){
      const float* p = Whh + (size_t)n*H + ks*32 + q*8;  // B[k][n]=Whh[n][k]
      float4 a = *(const float4*)p;
      float4 b = *(const float4*)(p+4);
      half8_t f;
      f[0]=(_Float16)(a.x*sc); f[1]=(_Float16)(a.y*sc); f[2]=(_Float16)(a.z*sc); f[3]=(_Float16)(a.w*sc);
      f[4]=(_Float16)(b.x*sc); f[5]=(_Float16)(b.y*sc); f[6]=(_Float16)(b.z*sc); f[7]=(_Float16)(b.w*sc);
      P.bw[g][ks] = f;
    }
  }
}

// Decoder fold: Wcomb = Whh + Wih*Wfc, b' = b + Wih*bfc, then *sc.
// PINNED: explicit fmaf, deterministic (5-for-5 at 1 bf16 ulp: R11-R15).
__device__ __forceinline__ void load_phase_dec(PhaseConsts& P, const float* __restrict__ Whh,
                                               const float* __restrict__ Wih,
                                               const float* __restrict__ bih,
                                               const float* __restrict__ bhh,
                                               const float* __restrict__ Wfc,
                                               const float* __restrict__ bfc,
                                               int wv, int l15, int q){
#pragma unroll
  for(int g=0; g<4; g++){
    const float sc = (g==2) ? LOG2E2 : LOG2E;
    const int n = g*H + 16*wv + l15;
    const float wi0 = Wih[n*D + 0];
    const float wi1 = Wih[n*D + 1];
    P.bs[g] = fmaf(wi1, bfc[1], fmaf(wi0, bfc[0], bih[n] + bhh[n])) * sc;
    P.w0[g] = wi0 * sc;
    P.w1[g] = wi1 * sc;
#pragma unroll
    for(int ks=0; ks<4; ks++){
      const float* p  = Whh + (size_t)n*H + ks*32 + q*8;
      const float* f0 = Wfc + 0*H + ks*32 + q*8;
      const float* f1 = Wfc + 1*H + ks*32 + q*8;
      half8_t f;
#pragma unroll
      for(int j=0;j<8;j++){
        f[j] = (_Float16)(fmaf(wi1, f1[j], fmaf(wi0, f0[j], p[j])) * sc);
      }
      P.bw[g][ks] = f;
    }
  }
}

// One LSTM cell step for 32 rows (two 16-row m-halves, independent accumulators).
// h read from hsh[cur] (single fp16 plane), x from xsrc[32][2] (only when HASX),
// new h written to hsh[cur^1]. c per-lane fp32. One LDS-only barrier.
// acc values are PRE-SCALED gate args (log2e folded in weights).
// MERGED-RCP epilogue (R16): with Ei=2^-ai, Ef=2^-af, Eg=2^ag, Eo=2^-ao:
//   cc = [c*(Eg+1)(1+Ei) + (Eg-1)(1+Ef)] / [(1+Ef)(Eg+1)(1+Ei)]   (1 rcp, was 3)
//   h  = (Ecc-1) / [(Ecc+1)(1+Eo)],  Ecc = 2^(min(cc,30)*2log2e)  (1 rcp, was 2)
// 7 trans/row instead of 10. Overflow audit: |preact·sc| <= ~38 -> denoms <= 2^76;
// cc clamp at 30 (tanh(30)==1 in f32) caps d2 <= ~2^106 < 2^127. No inf/NaN path.
template<bool HASX>
__device__ __forceinline__ void cell_step(_Float16 (*hsh)[M][HP], int cur,
                                          const float* __restrict__ xsrc,
                                          const PhaseConsts& P, float (&c)[2][4],
                                          int wv, int l15, int q){
  float4_t acc[2][4];
  if constexpr (HASX){
#pragma unroll
    for(int mh=0; mh<2; mh++){
      float x0[4], x1[4];
#pragma unroll
      for(int r=0; r<4; r++){
        x0[r] = xsrc[(mh*16 + 4*q+r)*2 + 0];
        x1[r] = xsrc[(mh*16 + 4*q+r)*2 + 1];
      }
#pragma unroll
      for(int g=0; g<4; g++)
#pragma unroll
        for(int r=0; r<4; r++)
          acc[mh][g][r] = fmaf(P.w1[g], x1[r], fmaf(P.w0[g], x0[r], P.bs[g]));
    }
  } else {
#pragma unroll
    for(int mh=0; mh<2; mh++)
#pragma unroll
      for(int g=0; g<4; g++)
#pragma unroll
        for(int r=0; r<4; r++)
          acc[mh][g][r] = P.bs[g];
  }

#pragma unroll
  for(int ks=0; ks<4; ks++){
#pragma unroll
    for(int mh=0; mh<2; mh++){
      const half8_t a = *(const half8_t*)&hsh[cur][mh*16 + l15][ks*32 + q*8];
#pragma unroll
      for(int g=0; g<4; g++){
        acc[mh][g] = __builtin_amdgcn_mfma_f32_16x16x32_f16(a, P.bw[g][ks], acc[mh][g], 0,0,0);
      }
    }
  }
  const int nxt = cur ^ 1;
  const int u = 16*wv + l15;
#pragma unroll
  for(int mh=0; mh<2; mh++){
#pragma unroll
    for(int r=0; r<4; r++){
      const float Ei = exp2_f(-acc[mh][0][r]);
      const float Ef = exp2_f(-acc[mh][1][r]);
      const float Eg = exp2_f( acc[mh][2][r]);
      const float Eo = exp2_f(-acc[mh][3][r]);
      const float tf  = 1.f + Ef;
      const float dig = (Eg + 1.f) * (1.f + Ei);
      const float m1  = (Eg - 1.f) * tf;
      const float num = fmaf(c[mh][r], dig, m1);
      const float den = dig * tf;
      const float cc  = num * fast_rcp(den);
      c[mh][r] = cc;
      const float ccl = fminf(cc, 30.f);
      const float Ecc = exp2_f(ccl * LOG2E2);
      const float d2  = (Ecc + 1.f) * (1.f + Eo);
      const float hv  = (Ecc - 1.f) * fast_rcp(d2);
      const int m = mh*16 + 4*q + r;
      hsh[nxt][m][u] = (_Float16)hv;
    }
  }
  lds_barrier();
}

// LayerNorm over 128 units for 32 rows; all 512 threads, 16 threads/row.
__device__ __forceinline__ void layernorm32(const float (*src)[FP], float (*dst)[FP],
                                            const float* __restrict__ g,
                                            const float* __restrict__ b, int tid){
  const int m = tid >> 4, sub = tid & 15;
  float v[8];
  float s = 0.f, s2 = 0.f;
#pragma unroll
  for(int j=0;j<8;j++){ v[j] = src[m][sub*8+j]; s += v[j]; s2 = fmaf(v[j], v[j], s2); }
#pragma unroll
  for(int msk=1; msk<16; msk<<=1){ s += __shfl_xor(s, msk, 64); s2 += __shfl_xor(s2, msk, 64); }
  const float mean = s * (1.f/H);
  const float var  = fmaf(-mean, mean, s2 * (1.f/H));   // PINNED contraction
  const float inv  = rsqrtf(var + LN_EPS);
#pragma unroll
  for(int j=0;j<8;j++){
    const int u = sub*8+j;
    dst[m][u] = fmaf((v[j]-mean)*inv, g[u], b[u]);
  }
}

// Output-only FC via v_dot2_f32_f16: cs = h @ Wfc^T + bfc, fp16 Wfc copy.
// Writes global out ONLY (never feeds the recurrence).
// No barrier needed: hb rewritten two cell-steps later (barrier in between).
__device__ __forceinline__ void fc_out(const _Float16 (*hb)[HP], const _Float16 (*wfch)[H],
                                       const float* __restrict__ bfcs,
                                       float* __restrict__ gout, int row0, int tid){
  const int m = tid >> 4, d = (tid >> 3) & 1, ch = tid & 7;
  const half2_t* hp2 = (const half2_t*)&hb[m][ch*16];
  const half2_t* wp2 = (const half2_t*)&wfch[d][ch*16];
  float s = 0.f;
#pragma unroll
  for(int j=0;j<8;j++) s = __builtin_amdgcn_fdot2(hp2[j], wp2[j], s, false);
  s += __shfl_xor(s, 1, 64); s += __shfl_xor(s, 2, 64); s += __shfl_xor(s, 4, 64);
  if(ch == 0){
    gout[(size_t)(row0+m)*D + d] = s + bfcs[d];
  }
}

// Step-0 delta: xb[m][d] = xlast[m][d] - (Wfc@h0 + bfc)[m][d]. All 512 threads.
// KEEPS the f32 Wfc path: this feeds the decoder recurrence (draw-sensitive).
__device__ __forceinline__ void fc_delta(const _Float16 (*hb)[HP], const float (*wfc)[H],
                                         const float* __restrict__ bfcs,
                                         const float* __restrict__ xlast,  // [M][D] contiguous
                                         float (*xb)[D], int tid){
  const int m = tid >> 4, d = (tid >> 3) & 1, ch = tid & 7;
  const _Float16* hp = &hb[m][ch*16];
  float s = 0.f;
#pragma unroll
  for(int j=0;j<16;j++) s = fmaf((float)hp[j], wfc[d][ch*16+j], s);
  s += __shfl_xor(s, 1, 64); s += __shfl_xor(s, 2, 64); s += __shfl_xor(s, 4, 64);
  if(ch == 0){
    xb[m][d] = xlast[m*D + d] - (s + bfcs[d]);
  }
}

__global__ __launch_bounds__(NTH, 2) void traj_kernel(
    const float* __restrict__ pos, const float* __restrict__ speed,
    const float* __restrict__ Wih_pe, const float* __restrict__ Whh_pe,
    const float* __restrict__ bih_pe, const float* __restrict__ bhh_pe,
    const float* __restrict__ Wih_se, const float* __restrict__ Whh_se,
    const float* __restrict__ bih_se, const float* __restrict__ bhh_se,
    const float* __restrict__ ln_g, const float* __restrict__ ln_b,
    const float* __restrict__ Wih_sd, const float* __restrict__ Whh_sd,
    const float* __restrict__ bih_sd, const float* __restrict__ bhh_sd,
    const float* __restrict__ Wih_pd, const float* __restrict__ Whh_pd,
    const float* __restrict__ bih_pd, const float* __restrict__ bhh_pd,
    const float* __restrict__ Wfc, const float* __restrict__ bfc,
    float* __restrict__ out)
{
  __shared__ __align__(16) _Float16 hsh[2][M][HP];    // [buf][m][u]  ~17.4 KB
  __shared__ float tmpf[M][FP];                        // ~16.9 KB each
  __shared__ float hpoN[M][FP];
  __shared__ float cpoN[M][FP];
  __shared__ float seqx[2][T_OBS][M][D];               // ~10.2 KB
  __shared__ float xbuf[M][D];
  __shared__ float wfcs[D][H];
  __shared__ __align__(16) _Float16 wfch[D][H];        // fp16 Wfc for fc_out dot2
  __shared__ float bfcs[2];
  // total ~80.1 KB

  const int tid  = threadIdx.x;
  const int lane = tid & 63;
  const int wv   = tid >> 6;       // 0..7 -> unit group
  const int q    = lane >> 4;
  const int l15  = lane & 15;
  const int row0 = blockIdx.x * M;
  const int u    = 16*wv + l15;

  // ---- stage inputs ----
  for(int idx = tid; idx < 2*T_OBS*M*D; idx += NTH){
    const int chain = idx / (T_OBS*M*D);
    const int rem   = idx % (T_OBS*M*D);
    const int t = rem / (M*D), e = rem % (M*D);
    const float* src = chain ? speed : pos;
    seqx[chain][t][e>>1][e&1] = src[(size_t)t*BATCH*D + row0*D + e];
  }
  if(tid < D*H){
    wfcs[tid>>7][tid&127] = Wfc[tid];
    wfch[tid>>7][tid&127] = (_Float16)Wfc[tid];
  }
  if(tid < 2)   bfcs[tid] = bfc[tid];
  { int* hz = (int*)&hsh[0][0][0];                    // zero buf0 (M*HP fp16 = 2176 ints)
    for(int idx = tid; idx < M*HP/2; idx += NTH) hz[idx] = 0; }

  PhaseConsts P;
  float c[2][4];
  load_phase(P, Whh_pe, Wih_pe, bih_pe, bhh_pe, wv, l15, q);
#pragma unroll
  for(int mh=0;mh<2;mh++)
#pragma unroll
    for(int r=0;r<4;r++) c[mh][r] = 0.f;
  __syncthreads();

  // ---------- phase 1: pos encoder ----------
  int cur = 0;
  for(int t=0; t<T_OBS; t++){ cell_step<true>(hsh, cur, &seqx[0][t][0][0], P, c, wv, l15, q); cur ^= 1; }
  for(int idx=tid; idx<M*H; idx+=NTH){
    const int m = idx>>7, uu = idx&127;
    tmpf[m][uu] = (float)hsh[cur][m][uu];
  }
  __syncthreads();
  layernorm32(tmpf, hpoN, ln_g, ln_b, tid);
  __syncthreads();
#pragma unroll
  for(int mh=0;mh<2;mh++)
#pragma unroll
    for(int r=0;r<4;r++) tmpf[mh*16 + 4*q+r][u] = c[mh][r];
  __syncthreads();
  layernorm32(tmpf, cpoN, ln_g, ln_b, tid);
  __syncthreads();

  // ---------- phase 2: speed encoder ----------
  load_phase(P, Whh_se, Wih_se, bih_se, bhh_se, wv, l15, q);
#pragma unroll
  for(int mh=0;mh<2;mh++)
#pragma unroll
    for(int r=0;r<4;r++) c[mh][r] = 0.f;
  for(int idx=tid; idx<M*H; idx+=NTH){
    const int m = idx>>7, uu = idx&127;
    hsh[0][m][uu] = (_Float16)0.f;
  }
  cur = 0;
  __syncthreads();
  for(int t=0; t<T_OBS; t++){ cell_step<true>(hsh, cur, &seqx[1][t][0][0], P, c, wv, l15, q); cur ^= 1; }
  for(int idx=tid; idx<M*H; idx+=NTH){
    const int m = idx>>7, uu = idx&127;
    tmpf[m][uu] = (float)hsh[cur][m][uu];
  }
  __syncthreads();
  layernorm32(tmpf, tmpf, ln_g, ln_b, tid);
  __syncthreads();
  // hds = LN(hsp) + LN(hpo) -> hsh[0]
  for(int idx=tid; idx<M*H; idx+=NTH){
    const int m = idx>>7, uu = idx&127;
    hsh[0][m][uu] = (_Float16)(tmpf[m][uu] + hpoN[m][uu]);
  }
  __syncthreads();
  // cds = LN(csp) + LN(cpo)
#pragma unroll
  for(int mh=0;mh<2;mh++)
#pragma unroll
    for(int r=0;r<4;r++) tmpf[mh*16 + 4*q+r][u] = c[mh][r];
  __syncthreads();
  layernorm32(tmpf, tmpf, ln_g, ln_b, tid);
  __syncthreads();
#pragma unroll
  for(int mh=0;mh<2;mh++)
#pragma unroll
    for(int r=0;r<4;r++) c[mh][r] = tmpf[mh*16 + 4*q+r][u] + cpoN[mh*16 + 4*q+r][u];

  // ---------- phase 3: speed decoder (FC folded into recurrence) ----------
  load_phase_dec(P, Whh_sd, Wih_sd, bih_sd, bhh_sd, Wfc, bfc, wv, l15, q);
  // dx = x0 - (Wfc@h0 + bfc); h0 = hds already in hsh[0] (visible: barrier above)
  fc_delta(hsh[0], wfcs, bfcs, &seqx[1][T_OBS-1][0][0], xbuf, tid);
  __syncthreads();

  float* spd_out = out + (size_t)PRED*BATCH*D;
  cur = 0;
  cell_step<true>(hsh, cur, &xbuf[0][0], P, c, wv, l15, q);
  fc_out(hsh[cur^1], wfch, bfcs, spd_out, row0, tid);
  cur ^= 1;
  for(int t=1; t<PRED; t++){
    cell_step<false>(hsh, cur, nullptr, P, c, wv, l15, q);
    fc_out(hsh[cur^1], wfch, bfcs, spd_out + (size_t)t*BATCH*D, row0, tid);
    cur ^= 1;
  }
  __syncthreads();   // protect hsh buffer still being read by last fc_out before reuse

  // ---------- phase 4: pos decoder ----------
  for(int idx=tid; idx<M*H; idx+=NTH){
    const int m = idx>>7, uu = idx&127;
    hsh[0][m][uu] = (_Float16)hpoN[m][uu];
  }
#pragma unroll
  for(int mh=0;mh<2;mh++)
#pragma unroll
    for(int r=0;r<4;r++) c[mh][r] = cpoN[mh*16 + 4*q+r][u];
  load_phase_dec(P, Whh_pd, Wih_pd, bih_pd, bhh_pd, Wfc, bfc, wv, l15, q);
  __syncthreads();   // hsh[0] (h0 = LN(hpo)) visible
  fc_delta(hsh[0], wfcs, bfcs, &seqx[0][T_OBS-1][0][0], xbuf, tid);
  __syncthreads();   // xbuf visible

  cur = 0;
  cell_step<true>(hsh, cur, &xbuf[0][0], P, c, wv, l15, q);
  fc_out(hsh[cur^1], wfch, bfcs, out, row0, tid);
  cur ^= 1;
  for(int t=1; t<PRED; t++){
    cell_step<false>(hsh, cur, nullptr, P, c, wv, l15, q);
    fc_out(hsh[cur^1], wfch, bfcs, out + (size_t)t*BATCH*D, row0, tid);
    cur ^= 1;
  }
}

extern "C" void kernel_launch(void* const* d_in, const int* in_sizes, int n_in,
                              void* d_out, int out_size, void* d_ws, size_t ws_size,
                              hipStream_t stream)
{
  const float* pos    = (const float*)d_in[0];
  const float* speed  = (const float*)d_in[1];
  const float* Wih_pe = (const float*)d_in[2];
  const float* Whh_pe = (const float*)d_in[3];
  const float* bih_pe = (const float*)d_in[4];
  const float* bhh_pe = (const float*)d_in[5];
  const float* Wih_se = (const float*)d_in[6];
  const float* Whh_se = (const float*)d_in[7];
  const float* bih_se = (const float*)d_in[8];
  const float* bhh_se = (const float*)d_in[9];
  const float* ln_g   = (const float*)d_in[10];
  const float* ln_b   = (const float*)d_in[11];
  const float* Wih_sd = (const float*)d_in[12];
  const float* Whh_sd = (const float*)d_in[13];
  const float* bih_sd = (const float*)d_in[14];
  const float* bhh_sd = (const float*)d_in[15];
  const float* Wih_pd = (const float*)d_in[16];
  const float* Whh_pd = (const float*)d_in[17];
  const float* bih_pd = (const float*)d_in[18];
  const float* bhh_pd = (const float*)d_in[19];
  const float* Wfc    = (const float*)d_in[20];
  const float* bfc    = (const float*)d_in[21];

  traj_kernel<<<BATCH/M, NTH, 0, stream>>>(
      pos, speed, Wih_pe, Whh_pe, bih_pe, bhh_pe,
      Wih_se, Whh_se, bih_se, bhh_se, ln_g, ln_b,
      Wih_sd, Whh_sd, bih_sd, bhh_sd, Wih_pd, Whh_pd, bih_pd, bhh_pd,
      Wfc, bfc, (float*)d_out);
}